// Round 3
// baseline (233.946 us; speedup 1.0000x reference)
//
#include <hip/hip_runtime.h>

typedef float f32x4 __attribute__((ext_vector_type(4)));
typedef short s16x8 __attribute__((ext_vector_type(8)));
typedef unsigned int u32x4 __attribute__((ext_vector_type(4)));

__device__ __forceinline__ unsigned short f2bf(float f) {
  unsigned int u = __float_as_uint(f);
  u += 0x7fffu + ((u >> 16) & 1u);
  return (unsigned short)(u >> 16);
}

template <typename T>
__device__ __forceinline__ void gload16(const T* g, T* l) {
  __builtin_amdgcn_global_load_lds(
      (const __attribute__((address_space(1))) void*)g,
      (__attribute__((address_space(3))) void*)l, 16, 0, 0);
}

// ---------------- GroupNorm stats: one block per (b,g) ----------------
__global__ __launch_bounds__(256) void gn_stats_k(const float* __restrict__ x,
                                                  float* __restrict__ meanv,
                                                  float* __restrict__ rstdv) {
  const int bg = blockIdx.x;
  const float4* base = (const float4*)(x + (size_t)bg * 8 * 4096);
  float s = 0.f, q = 0.f;
  for (int i = threadIdx.x; i < 8192; i += 256) {
    float4 v = base[i];
    s += v.x + v.y + v.z + v.w;
    q += v.x * v.x + v.y * v.y + v.z * v.z + v.w * v.w;
  }
  for (int o = 32; o; o >>= 1) { s += __shfl_down(s, o); q += __shfl_down(q, o); }
  __shared__ float ss[4], sq[4];
  const int wv = threadIdx.x >> 6;
  if ((threadIdx.x & 63) == 0) { ss[wv] = s; sq[wv] = q; }
  __syncthreads();
  if (threadIdx.x == 0) {
    s = ss[0] + ss[1] + ss[2] + ss[3];
    q = sq[0] + sq[1] + sq[2] + sq[3];
    float mu = s * (1.f / 32768.f);
    float var = q * (1.f / 32768.f) - mu * mu;
    meanv[bg] = mu;
    rstdv[bg] = rsqrtf(var + 1e-6f);
  }
}

// ------------- GroupNorm apply + transpose: write hT[b][t][c] bf16 -------------
__global__ __launch_bounds__(256) void gn_apply_t_k(const float* __restrict__ x,
    const float* __restrict__ gamma, const float* __restrict__ beta,
    const float* __restrict__ meanv, const float* __restrict__ rstdv,
    unsigned short* __restrict__ hT) {
  __shared__ unsigned short tile[64][72];
  const int b = blockIdx.z, c0 = blockIdx.y * 64, t0 = blockIdx.x * 64;
  const int tid = threadIdx.x;
  {
    const int tr = tid >> 4, tc = (tid & 15) * 4;
    const float* xb = x + ((size_t)b * 256 + c0) * 4096 + t0;
    for (int p2 = 0; p2 < 4; ++p2) {
      int cl = p2 * 16 + tr;
      int c = c0 + cl;
      int bg = b * 32 + (c >> 3);
      float ga = gamma[c] * rstdv[bg];
      float be = beta[c] - meanv[bg] * ga;
      float4 v = *(const float4*)(xb + (size_t)cl * 4096 + tc);
      tile[cl][tc + 0] = f2bf(v.x * ga + be);
      tile[cl][tc + 1] = f2bf(v.y * ga + be);
      tile[cl][tc + 2] = f2bf(v.z * ga + be);
      tile[cl][tc + 3] = f2bf(v.w * ga + be);
    }
  }
  __syncthreads();
  {
    const int orow = tid >> 3, oc = (tid & 7) * 8;
    unsigned short* hb = hT + ((size_t)b * 4096 + t0) * 256 + c0;
    for (int p2 = 0; p2 < 2; ++p2) {
      int tl = p2 * 32 + orow;
      s16x8 w;
#pragma unroll
      for (int j = 0; j < 8; ++j) w[j] = (short)tile[oc + j][tl];
      *(s16x8*)(hb + (size_t)tl * 256 + oc) = w;
    }
  }
}

// ---------------- generic 64x64-tile MFMA GEMM (projections) ----------------
enum { EPI_WT = 0, EPI_PB = 1, EPI_FIN = 3 };

template <bool AF32, int EPI>
__global__ __launch_bounds__(256) void gemm64_k(
    const void* __restrict__ Ap, long long sA, int lda,
    const unsigned short* __restrict__ Bp, long long sB, int ldb,
    void* __restrict__ Op, long long sO, int ldo,
    const float* __restrict__ bias,
    const float* __restrict__ xadd, long long sX,
    float scale, int K) {
  __shared__ s16x8 lsA[4][64];
  __shared__ s16x8 lsB[4][64];
  const int tid = threadIdx.x;
  const int m0 = blockIdx.y * 64, n0 = blockIdx.x * 64;
  const int z = blockIdx.z;
  const int lane = tid & 63, wv = tid >> 6;
  const int lrow = lane & 15, lg = lane >> 4;
  const int srow = tid >> 2, scg = tid & 3;
  const int swrow = srow ^ (scg << 1);

  f32x4 acc[4];
#pragma unroll
  for (int i = 0; i < 4; ++i) acc[i] = (f32x4){0.f, 0.f, 0.f, 0.f};

  const unsigned short* Bb = Bp + (size_t)z * sB + (size_t)(n0 + srow) * ldb + scg * 8;

  for (int k0 = 0; k0 < K; k0 += 32) {
    if (AF32) {
      const float* ap = (const float*)Ap + (size_t)z * sA + (size_t)(m0 + srow) * lda + k0 + scg * 8;
      float4 v0 = *(const float4*)ap;
      float4 v1 = *(const float4*)(ap + 4);
      s16x8 w;
      w[0] = (short)f2bf(v0.x); w[1] = (short)f2bf(v0.y);
      w[2] = (short)f2bf(v0.z); w[3] = (short)f2bf(v0.w);
      w[4] = (short)f2bf(v1.x); w[5] = (short)f2bf(v1.y);
      w[6] = (short)f2bf(v1.z); w[7] = (short)f2bf(v1.w);
      lsA[scg][swrow] = w;
    } else {
      const unsigned short* ap = (const unsigned short*)Ap + (size_t)z * sA + (size_t)(m0 + srow) * lda + k0 + scg * 8;
      lsA[scg][swrow] = *(const s16x8*)ap;
    }
    lsB[scg][swrow] = *(const s16x8*)(Bb + k0);
    __syncthreads();
    s16x8 af = lsA[lg][(wv * 16 + lrow) ^ (lg << 1)];
#pragma unroll
    for (int nt = 0; nt < 4; ++nt) {
      s16x8 bf = lsB[lg][(nt * 16 + lrow) ^ (lg << 1)];
      acc[nt] = __builtin_amdgcn_mfma_f32_16x16x32_bf16(af, bf, acc[nt], 0, 0, 0);
    }
    __syncthreads();
  }

  const int mb = m0 + wv * 16 + lg * 4;
  float bv0 = 0.f, bv1 = 0.f, bv2 = 0.f, bv3 = 0.f;
  if (bias) { bv0 = bias[mb]; bv1 = bias[mb + 1]; bv2 = bias[mb + 2]; bv3 = bias[mb + 3]; }
#pragma unroll
  for (int nt = 0; nt < 4; ++nt) {
    const int n = n0 + nt * 16 + lrow;
    if (EPI == EPI_WT) {
      ushort4 pk;
      pk.x = f2bf((acc[nt][0] + bv0) * scale);
      pk.y = f2bf((acc[nt][1] + bv1) * scale);
      pk.z = f2bf((acc[nt][2] + bv2) * scale);
      pk.w = f2bf((acc[nt][3] + bv3) * scale);
      *(ushort4*)((unsigned short*)Op + (size_t)z * sO + (size_t)n * ldo + mb) = pk;
    } else if (EPI == EPI_PB) {
      unsigned short* o = (unsigned short*)Op + (size_t)z * sO;
      o[(size_t)(mb + 0) * ldo + n] = f2bf(acc[nt][0] + bv0);
      o[(size_t)(mb + 1) * ldo + n] = f2bf(acc[nt][1] + bv1);
      o[(size_t)(mb + 2) * ldo + n] = f2bf(acc[nt][2] + bv2);
      o[(size_t)(mb + 3) * ldo + n] = f2bf(acc[nt][3] + bv3);
    } else {
      float* o = (float*)Op + (size_t)z * sO;
      const float* xa = xadd + (size_t)z * sX;
      o[(size_t)(mb + 0) * ldo + n] = acc[nt][0] + bv0 + xa[(size_t)(mb + 0) * ldo + n];
      o[(size_t)(mb + 1) * ldo + n] = acc[nt][1] + bv1 + xa[(size_t)(mb + 1) * ldo + n];
      o[(size_t)(mb + 2) * ldo + n] = acc[nt][2] + bv2 + xa[(size_t)(mb + 2) * ldo + n];
      o[(size_t)(mb + 3) * ldo + n] = acc[nt][3] + bv3 + xa[(size_t)(mb + 3) * ldo + n];
    }
  }
}

// ------- pass 1: S + online stats; stores S^T bf16 tiled [b][k/64][q/64][64][64] -------
#define KS1 4
__global__ __launch_bounds__(256) void attn_stats2_k(
    const unsigned short* __restrict__ qT,
    const unsigned short* __restrict__ kT,
    float* __restrict__ pm, float* __restrict__ pl,
    unsigned short* __restrict__ ST, int b0) {
  __shared__ unsigned short kbuf[2][64 * 256];
  const int tid = threadIdx.x;
  const int z = blockIdx.z, b = b0 + z;
  const int Q0 = blockIdx.x * 128;
  const int kc = blockIdx.y;
  const int lane = tid & 63, w = tid >> 6;
  const int lrow = lane & 15, lg = lane >> 4;

  const unsigned short* qb = qT + (size_t)b * (4096 * 256);
  const unsigned short* kb = kT + (size_t)b * (4096 * 256);

  s16x8 af[2][8];
#pragma unroll
  for (int mt = 0; mt < 2; ++mt)
#pragma unroll
    for (int ks = 0; ks < 8; ++ks)
      af[mt][ks] = *(const s16x8*)(qb + (size_t)(Q0 + mt * 64 + w * 16 + lrow) * 256 + ks * 32 + lg * 8);

  float st_m[8], st_l[8];
#pragma unroll
  for (int s = 0; s < 8; ++s) { st_m[s] = 0.f; st_l[s] = 0.f; }

  int cur = 0;
  {
    const unsigned short* src = kb + (size_t)(kc * 1024) * 256;
#pragma unroll
    for (int rep = 0; rep < 8; ++rep) {
      int i = rep * 256 + tid;
      int row = i >> 5, c8 = i & 31;
      int c8s = c8 ^ (row & 7);
      gload16(src + (size_t)row * 256 + c8s * 8, &kbuf[0][(i - lane) * 8]);
    }
  }
  __syncthreads();

  for (int it = 0; it < 16; ++it) {
    if (it + 1 < 16) {
      const unsigned short* src = kb + (size_t)(kc * 1024 + (it + 1) * 64) * 256;
#pragma unroll
      for (int rep = 0; rep < 8; ++rep) {
        int i = rep * 256 + tid;
        int row = i >> 5, c8 = i & 31;
        int c8s = c8 ^ (row & 7);
        gload16(src + (size_t)row * 256 + c8s * 8, &kbuf[cur ^ 1][(i - lane) * 8]);
      }
    }
    f32x4 acc[2][4];
#pragma unroll
    for (int mt = 0; mt < 2; ++mt)
#pragma unroll
      for (int nt = 0; nt < 4; ++nt) acc[mt][nt] = (f32x4){0.f, 0.f, 0.f, 0.f};
#pragma unroll
    for (int ks = 0; ks < 8; ++ks) {
#pragma unroll
      for (int nt = 0; nt < 4; ++nt) {
        int row = nt * 16 + lrow;
        int ch = (ks * 4 + lg) ^ (row & 7);
        s16x8 bf = *(const s16x8*)&kbuf[cur][row * 256 + ch * 8];
        acc[0][nt] = __builtin_amdgcn_mfma_f32_16x16x32_bf16(af[0][ks], bf, acc[0][nt], 0, 0, 0);
        acc[1][nt] = __builtin_amdgcn_mfma_f32_16x16x32_bf16(af[1][ks], bf, acc[1][nt], 0, 0, 0);
      }
    }
    // round to bf16, store S^T tiles, update stats from ROUNDED values (exact consistency)
    const int kt = kc * 16 + it;
#pragma unroll
    for (int mt = 0; mt < 2; ++mt) {
      float sb[4][4];
      unsigned short* tb = ST + (((size_t)(z * 64 + kt)) * 64 + (Q0 >> 6) + mt) * 4096;
#pragma unroll
      for (int nt = 0; nt < 4; ++nt) {
        ushort4 pk;
#pragma unroll
        for (int j = 0; j < 4; ++j) {
          unsigned short us = f2bf(acc[mt][nt][j]);
          ((unsigned short*)&pk)[j] = us;
          sb[nt][j] = __uint_as_float((unsigned int)us << 16);
        }
        *(ushort4*)(tb + (size_t)(nt * 16 + lrow) * 64 + w * 16 + lg * 4) = pk;
      }
#pragma unroll
      for (int j = 0; j < 4; ++j) {
        int s = mt * 4 + j;
        float mx = fmaxf(fmaxf(sb[0][j], sb[1][j]), fmaxf(sb[2][j], sb[3][j]));
        float mn = fmaxf(st_m[s], mx);
        st_l[s] = st_l[s] * __expf(st_m[s] - mn) +
                  __expf(sb[0][j] - mn) + __expf(sb[1][j] - mn) +
                  __expf(sb[2][j] - mn) + __expf(sb[3][j] - mn);
        st_m[s] = mn;
      }
    }
    __syncthreads();
    cur ^= 1;
  }
#pragma unroll
  for (int s = 0; s < 8; ++s) {
    float m = st_m[s], l = st_l[s];
#pragma unroll
    for (int o = 1; o < 16; o <<= 1) {
      float mo = __shfl_xor(m, o);
      float lo = __shfl_xor(l, o);
      float mn = fmaxf(m, mo);
      l = l * __expf(m - mn) + lo * __expf(mo - mn);
      m = mn;
    }
    st_m[s] = m; st_l[s] = l;
  }
  if (lrow == 0) {
    float* pmb = pm + ((size_t)b * KS1 + kc) * 4096;
    float* plb = pl + ((size_t)b * KS1 + kc) * 4096;
#pragma unroll
    for (int mt = 0; mt < 2; ++mt)
#pragma unroll
      for (int j = 0; j < 4; ++j) {
        int q = Q0 + mt * 64 + w * 16 + lg * 4 + j;
        pmb[q] = st_m[mt * 4 + j];
        plb[q] = st_l[mt * 4 + j];
      }
  }
}

__global__ __launch_bounds__(256) void stats_merge_k(const float* __restrict__ pm,
    const float* __restrict__ pl, float* __restrict__ ma, float* __restrict__ ra, int b0) {
  int i = blockIdx.x * 256 + threadIdx.x;
  int b = b0 + (i >> 12), q = i & 4095;
  const float* pmb = pm + (size_t)b * KS1 * 4096 + q;
  const float* plb = pl + (size_t)b * KS1 * 4096 + q;
  float m = -1e30f;
#pragma unroll
  for (int c = 0; c < KS1; ++c) m = fmaxf(m, pmb[(size_t)c * 4096]);
  float l = 0.f;
#pragma unroll
  for (int c = 0; c < KS1; ++c) l += plb[(size_t)c * 4096] * __expf(pmb[(size_t)c * 4096] - m);
  ma[(size_t)b * 4096 + q] = m;
  ra[(size_t)b * 4096 + q] = 1.f / l;
}

// ------------- pass 2: PV from stored S^T. grid (T/32, G), 256 thr -------------
__global__ __launch_bounds__(256) void attn_pv2_k(
    const unsigned short* __restrict__ ST,
    const unsigned short* __restrict__ vb,   // [B][C][T]
    const float* __restrict__ ma, const float* __restrict__ ra,
    unsigned short* __restrict__ aT, int b0) {
  __shared__ unsigned short vbuf[256 * 64];  // 32KB
  __shared__ unsigned short P[32 * 72];      // 4.5KB
  const int tid = threadIdx.x;
  const int z = blockIdx.y, b = b0 + z;
  const int kb = blockIdx.x, K0 = kb * 32;
  const int lane = tid & 63, w = tid >> 6;
  const int lrow = lane & 15, lg = lane >> 4;
  const int kk_e = tid >> 3, o_e = tid & 7;          // exp-phase role
  const int os_e = o_e ^ (kk_e & 7);                 // swizzled P chunk

  const unsigned short* vg = vb + (size_t)b * (4096 * 256);
  const unsigned short* stg = ST + ((size_t)(z * 64 + (kb >> 1)) * 64) * 4096 + (kb & 1) * 2048;
  const float* mg = ma + (size_t)b * 4096;
  const float* rg = ra + (size_t)b * 4096;

  f32x4 oacc[4][2];
#pragma unroll
  for (int mt = 0; mt < 4; ++mt)
#pragma unroll
    for (int nt = 0; nt < 2; ++nt) oacc[mt][nt] = (f32x4){0.f, 0.f, 0.f, 0.f};

  // prologue: stage v[0]; load stv0 + m/r
  {
#pragma unroll
    for (int rep = 0; rep < 8; ++rep) {
      int i = rep * 256 + tid;
      int row = i >> 3, c8 = i & 7, c8s = c8 ^ (row & 7);
      gload16(vg + (size_t)row * 4096 + c8s * 8, &vbuf[(i - lane) * 8]);
    }
  }
  u32x4 sv = *(const u32x4*)(stg + (size_t)tid * 8);
  float4 m4a = *(const float4*)(mg + o_e * 8);
  float4 m4b = *(const float4*)(mg + o_e * 8 + 4);
  float4 r4a = *(const float4*)(rg + o_e * 8);
  float4 r4b = *(const float4*)(rg + o_e * 8 + 4);

  for (int qi = 0; qi < 64; ++qi) {
    // (a) exp: 8 values from registers -> P (swizzled, conflict-free)
    {
      u32x4 pk;
      float mv[8] = {m4a.x, m4a.y, m4a.z, m4a.w, m4b.x, m4b.y, m4b.z, m4b.w};
      float rv[8] = {r4a.x, r4a.y, r4a.z, r4a.w, r4b.x, r4b.y, r4b.z, r4b.w};
#pragma unroll
      for (int p = 0; p < 4; ++p) {
        unsigned int u = sv[p];
        float s0 = __uint_as_float(u << 16);
        float s1 = __uint_as_float(u & 0xffff0000u);
        float p0 = __expf(s0 - mv[p * 2 + 0]) * rv[p * 2 + 0];
        float p1 = __expf(s1 - mv[p * 2 + 1]) * rv[p * 2 + 1];
        pk[p] = (unsigned int)f2bf(p0) | ((unsigned int)f2bf(p1) << 16);
      }
      *(u32x4*)&P[kk_e * 72 + os_e * 8] = pk;
    }
    __syncthreads();  // P visible; v[qi] staged (vmcnt drained)
    // (d) PV: oacc[c][k] += v[c][q-tile] * P^T[k][q-tile]
#pragma unroll
    for (int ks = 0; ks < 2; ++ks) {
      s16x8 avf[4], pf[2];
#pragma unroll
      for (int mt = 0; mt < 4; ++mt) {
        int crow = w * 64 + mt * 16 + lrow;
        int ch = (ks * 4 + lg) ^ (crow & 7);
        avf[mt] = *(const s16x8*)&vbuf[crow * 64 + ch * 8];
      }
#pragma unroll
      for (int nt = 0; nt < 2; ++nt) {
        int kk = nt * 16 + lrow;
        int ch = (ks * 4 + lg) ^ (kk & 7);
        pf[nt] = *(const s16x8*)&P[kk * 72 + ch * 8];
      }
#pragma unroll
      for (int mt = 0; mt < 4; ++mt)
#pragma unroll
        for (int nt = 0; nt < 2; ++nt)
          oacc[mt][nt] = __builtin_amdgcn_mfma_f32_16x16x32_bf16(avf[mt], pf[nt], oacc[mt][nt], 0, 0, 0);
    }
    __syncthreads();  // vbuf + P consumed
    // (f)+(b): issue next tile loads; they fly across exp phase of next iter
    if (qi < 63) {
      const int q1 = (qi + 1) * 64;
#pragma unroll
      for (int rep = 0; rep < 8; ++rep) {
        int i = rep * 256 + tid;
        int row = i >> 3, c8 = i & 7, c8s = c8 ^ (row & 7);
        gload16(vg + (size_t)row * 4096 + q1 + c8s * 8, &vbuf[(i - lane) * 8]);
      }
      sv = *(const u32x4*)(stg + (size_t)(qi + 1) * 4096 + tid * 8);
      m4a = *(const float4*)(mg + q1 + o_e * 8);
      m4b = *(const float4*)(mg + q1 + o_e * 8 + 4);
      r4a = *(const float4*)(rg + q1 + o_e * 8);
      r4b = *(const float4*)(rg + q1 + o_e * 8 + 4);
    }
  }
  // epilogue: aT[b][k][c]
  unsigned short* ab = aT + (size_t)b * (4096 * 256);
#pragma unroll
  for (int mt = 0; mt < 4; ++mt)
#pragma unroll
    for (int nt = 0; nt < 2; ++nt) {
      int k = K0 + nt * 16 + lrow;
      int c = w * 64 + mt * 16 + lg * 4;
      ushort4 pk;
      pk.x = f2bf(oacc[mt][nt][0]);
      pk.y = f2bf(oacc[mt][nt][1]);
      pk.z = f2bf(oacc[mt][nt][2]);
      pk.w = f2bf(oacc[mt][nt][3]);
      *(ushort4*)(ab + (size_t)k * 256 + c) = pk;
    }
}

extern "C" void kernel_launch(void* const* d_in, const int* in_sizes, int n_in,
                              void* d_out, int out_size, void* d_ws, size_t ws_size,
                              hipStream_t stream) {
  const float* x   = (const float*)d_in[0];
  const float* gns = (const float*)d_in[1];
  const float* gnb = (const float*)d_in[2];
  const float* wq  = (const float*)d_in[3];
  const float* bq  = (const float*)d_in[4];
  const float* wk  = (const float*)d_in[5];
  const float* bk  = (const float*)d_in[6];
  const float* wvp = (const float*)d_in[7];
  const float* bv  = (const float*)d_in[8];
  const float* wo  = (const float*)d_in[9];
  const float* bo  = (const float*)d_in[10];
  float* out = (float*)d_out;

  const int B = 4, C = 256, T = 4096;
  const long long TCe = (long long)T * C;

  char* p = (char*)d_ws;
  unsigned short* hT = (unsigned short*)p; p += (size_t)B * TCe * 2;
  unsigned short* qT = (unsigned short*)p; p += (size_t)B * TCe * 2;
  unsigned short* kT = (unsigned short*)p; p += (size_t)B * TCe * 2;
  unsigned short* vb = (unsigned short*)p; p += (size_t)B * TCe * 2;
  unsigned short* aT = (unsigned short*)p; p += (size_t)B * TCe * 2;
  float* gmean = (float*)p; p += 512;
  float* grstd = (float*)p; p += 512;
  float* pm = (float*)p; p += (size_t)B * KS1 * T * 4;
  float* pl = (float*)p; p += (size_t)B * KS1 * T * 4;
  float* ma = (float*)p; p += (size_t)B * T * 4;
  float* ra = (float*)p; p += (size_t)B * T * 4;
  unsigned short* ST = (unsigned short*)p;
  size_t used = (size_t)((char*)ST - (char*)d_ws);
  size_t avail = ws_size > used ? ws_size - used : 0;
  size_t perb = (size_t)T * T * 2;  // 32MB per batch of S^T
  int G = (avail >= 4 * perb) ? 4 : (avail >= 2 * perb) ? 2 : 1;

  // 1) GroupNorm
  gn_stats_k<<<B * 32, 256, 0, stream>>>(x, gmean, grstd);
  gn_apply_t_k<<<dim3(T / 64, C / 64, B), 256, 0, stream>>>(x, gns, gnb, gmean, grstd, hT);

  // 2) QKV projections (q folded with C^-0.5 = 1/16)
  gemm64_k<true, EPI_WT><<<dim3(T / 64, C / 64, B), 256, 0, stream>>>(
      wq, 0, C, hT, TCe, C, qT, TCe, C, bq, nullptr, 0, 0.0625f, C);
  gemm64_k<true, EPI_WT><<<dim3(T / 64, C / 64, B), 256, 0, stream>>>(
      wk, 0, C, hT, TCe, C, kT, TCe, C, bk, nullptr, 0, 1.0f, C);
  gemm64_k<true, EPI_PB><<<dim3(T / 64, C / 64, B), 256, 0, stream>>>(
      wvp, 0, C, hT, TCe, C, vb, TCe, T, bv, nullptr, 0, 1.0f, C);

  // 3) attention in batch groups sized by workspace
  for (int b0 = 0; b0 < B; b0 += G) {
    attn_stats2_k<<<dim3(T / 128, KS1, G), 256, 0, stream>>>(qT, kT, pm, pl, ST, b0);
    stats_merge_k<<<G * T / 256, 256, 0, stream>>>(pm, pl, ma, ra, b0);
    attn_pv2_k<<<dim3(T / 32, G), 256, 0, stream>>>(ST, vb, ma, ra, aT, b0);
  }

  // 4) final projection + bias + residual
  gemm64_k<true, EPI_FIN><<<dim3(T / 64, C / 64, B), 256, 0, stream>>>(
      wo, 0, C, aT, TCe, C, out, TCe, T, bo, x, TCe, 1.0f, C);
}

// Round 4
// 225.148 us; speedup vs baseline: 1.0391x; 1.0391x over previous
//
#include <hip/hip_runtime.h>

typedef float f32x4 __attribute__((ext_vector_type(4)));
typedef short s16x8 __attribute__((ext_vector_type(8)));
typedef unsigned int u32x4 __attribute__((ext_vector_type(4)));

__device__ __forceinline__ unsigned short f2bf(float f) {
  unsigned int u = __float_as_uint(f);
  u += 0x7fffu + ((u >> 16) & 1u);
  return (unsigned short)(u >> 16);
}

template <typename T>
__device__ __forceinline__ void gload16(const T* g, T* l) {
  __builtin_amdgcn_global_load_lds(
      (const __attribute__((address_space(1))) void*)g,
      (__attribute__((address_space(3))) void*)l, 16, 0, 0);
}

// ---------------- GroupNorm stats: one block per (b,g) ----------------
__global__ __launch_bounds__(256) void gn_stats_k(const float* __restrict__ x,
                                                  float* __restrict__ meanv,
                                                  float* __restrict__ rstdv) {
  const int bg = blockIdx.x;
  const float4* base = (const float4*)(x + (size_t)bg * 8 * 4096);
  float s = 0.f, q = 0.f;
  for (int i = threadIdx.x; i < 8192; i += 256) {
    float4 v = base[i];
    s += v.x + v.y + v.z + v.w;
    q += v.x * v.x + v.y * v.y + v.z * v.z + v.w * v.w;
  }
  for (int o = 32; o; o >>= 1) { s += __shfl_down(s, o); q += __shfl_down(q, o); }
  __shared__ float ss[4], sq[4];
  const int wv = threadIdx.x >> 6;
  if ((threadIdx.x & 63) == 0) { ss[wv] = s; sq[wv] = q; }
  __syncthreads();
  if (threadIdx.x == 0) {
    s = ss[0] + ss[1] + ss[2] + ss[3];
    q = sq[0] + sq[1] + sq[2] + sq[3];
    float mu = s * (1.f / 32768.f);
    float var = q * (1.f / 32768.f) - mu * mu;
    meanv[bg] = mu;
    rstdv[bg] = rsqrtf(var + 1e-6f);
  }
}

// ------------- GroupNorm apply + transpose: write hT[b][t][c] bf16 -------------
__global__ __launch_bounds__(256) void gn_apply_t_k(const float* __restrict__ x,
    const float* __restrict__ gamma, const float* __restrict__ beta,
    const float* __restrict__ meanv, const float* __restrict__ rstdv,
    unsigned short* __restrict__ hT) {
  __shared__ unsigned short tile[64][72];
  const int b = blockIdx.z, c0 = blockIdx.y * 64, t0 = blockIdx.x * 64;
  const int tid = threadIdx.x;
  {
    const int tr = tid >> 4, tc = (tid & 15) * 4;
    const float* xb = x + ((size_t)b * 256 + c0) * 4096 + t0;
    for (int p2 = 0; p2 < 4; ++p2) {
      int cl = p2 * 16 + tr;
      int c = c0 + cl;
      int bg = b * 32 + (c >> 3);
      float ga = gamma[c] * rstdv[bg];
      float be = beta[c] - meanv[bg] * ga;
      float4 v = *(const float4*)(xb + (size_t)cl * 4096 + tc);
      tile[cl][tc + 0] = f2bf(v.x * ga + be);
      tile[cl][tc + 1] = f2bf(v.y * ga + be);
      tile[cl][tc + 2] = f2bf(v.z * ga + be);
      tile[cl][tc + 3] = f2bf(v.w * ga + be);
    }
  }
  __syncthreads();
  {
    const int orow = tid >> 3, oc = (tid & 7) * 8;
    unsigned short* hb = hT + ((size_t)b * 4096 + t0) * 256 + c0;
    for (int p2 = 0; p2 < 2; ++p2) {
      int tl = p2 * 32 + orow;
      s16x8 w;
#pragma unroll
      for (int j = 0; j < 8; ++j) w[j] = (short)tile[oc + j][tl];
      *(s16x8*)(hb + (size_t)tl * 256 + oc) = w;
    }
  }
}

// ---------------- generic 64x64-tile MFMA GEMM (projections) ----------------
enum { EPI_WT = 0, EPI_PB = 1, EPI_FIN = 3 };

template <bool AF32, int EPI>
__global__ __launch_bounds__(256) void gemm64_k(
    const void* __restrict__ Ap, long long sA, int lda,
    const unsigned short* __restrict__ Bp, long long sB, int ldb,
    void* __restrict__ Op, long long sO, int ldo,
    const float* __restrict__ bias,
    const float* __restrict__ xadd, long long sX,
    float scale, int K) {
  __shared__ s16x8 lsA[4][64];
  __shared__ s16x8 lsB[4][64];
  const int tid = threadIdx.x;
  const int m0 = blockIdx.y * 64, n0 = blockIdx.x * 64;
  const int z = blockIdx.z;
  const int lane = tid & 63, wv = tid >> 6;
  const int lrow = lane & 15, lg = lane >> 4;
  const int srow = tid >> 2, scg = tid & 3;
  const int swrow = srow ^ (scg << 1);

  f32x4 acc[4];
#pragma unroll
  for (int i = 0; i < 4; ++i) acc[i] = (f32x4){0.f, 0.f, 0.f, 0.f};

  const unsigned short* Bb = Bp + (size_t)z * sB + (size_t)(n0 + srow) * ldb + scg * 8;

  for (int k0 = 0; k0 < K; k0 += 32) {
    if (AF32) {
      const float* ap = (const float*)Ap + (size_t)z * sA + (size_t)(m0 + srow) * lda + k0 + scg * 8;
      float4 v0 = *(const float4*)ap;
      float4 v1 = *(const float4*)(ap + 4);
      s16x8 w;
      w[0] = (short)f2bf(v0.x); w[1] = (short)f2bf(v0.y);
      w[2] = (short)f2bf(v0.z); w[3] = (short)f2bf(v0.w);
      w[4] = (short)f2bf(v1.x); w[5] = (short)f2bf(v1.y);
      w[6] = (short)f2bf(v1.z); w[7] = (short)f2bf(v1.w);
      lsA[scg][swrow] = w;
    } else {
      const unsigned short* ap = (const unsigned short*)Ap + (size_t)z * sA + (size_t)(m0 + srow) * lda + k0 + scg * 8;
      lsA[scg][swrow] = *(const s16x8*)ap;
    }
    lsB[scg][swrow] = *(const s16x8*)(Bb + k0);
    __syncthreads();
    s16x8 af = lsA[lg][(wv * 16 + lrow) ^ (lg << 1)];
#pragma unroll
    for (int nt = 0; nt < 4; ++nt) {
      s16x8 bf = lsB[lg][(nt * 16 + lrow) ^ (lg << 1)];
      acc[nt] = __builtin_amdgcn_mfma_f32_16x16x32_bf16(af, bf, acc[nt], 0, 0, 0);
    }
    __syncthreads();
  }

  const int mb = m0 + wv * 16 + lg * 4;
  float bv0 = 0.f, bv1 = 0.f, bv2 = 0.f, bv3 = 0.f;
  if (bias) { bv0 = bias[mb]; bv1 = bias[mb + 1]; bv2 = bias[mb + 2]; bv3 = bias[mb + 3]; }
#pragma unroll
  for (int nt = 0; nt < 4; ++nt) {
    const int n = n0 + nt * 16 + lrow;
    if (EPI == EPI_WT) {
      ushort4 pk;
      pk.x = f2bf((acc[nt][0] + bv0) * scale);
      pk.y = f2bf((acc[nt][1] + bv1) * scale);
      pk.z = f2bf((acc[nt][2] + bv2) * scale);
      pk.w = f2bf((acc[nt][3] + bv3) * scale);
      *(ushort4*)((unsigned short*)Op + (size_t)z * sO + (size_t)n * ldo + mb) = pk;
    } else if (EPI == EPI_PB) {
      unsigned short* o = (unsigned short*)Op + (size_t)z * sO;
      o[(size_t)(mb + 0) * ldo + n] = f2bf(acc[nt][0] + bv0);
      o[(size_t)(mb + 1) * ldo + n] = f2bf(acc[nt][1] + bv1);
      o[(size_t)(mb + 2) * ldo + n] = f2bf(acc[nt][2] + bv2);
      o[(size_t)(mb + 3) * ldo + n] = f2bf(acc[nt][3] + bv3);
    } else {
      float* o = (float*)Op + (size_t)z * sO;
      const float* xa = xadd + (size_t)z * sX;
      o[(size_t)(mb + 0) * ldo + n] = acc[nt][0] + bv0 + xa[(size_t)(mb + 0) * ldo + n];
      o[(size_t)(mb + 1) * ldo + n] = acc[nt][1] + bv1 + xa[(size_t)(mb + 1) * ldo + n];
      o[(size_t)(mb + 2) * ldo + n] = acc[nt][2] + bv2 + xa[(size_t)(mb + 2) * ldo + n];
      o[(size_t)(mb + 3) * ldo + n] = acc[nt][3] + bv3 + xa[(size_t)(mb + 3) * ldo + n];
    }
  }
}

// ------- pass 1: S + online stats; stores S^T bf16 tiled [b][k/64][q/64][64k][64q] -------
#define KS1 4
__global__ __launch_bounds__(256) void attn_stats2_k(
    const unsigned short* __restrict__ qT,
    const unsigned short* __restrict__ kT,
    float* __restrict__ pm, float* __restrict__ pl,
    unsigned short* __restrict__ ST, int b0) {
  __shared__ unsigned short kbuf[2][64 * 256];
  const int tid = threadIdx.x;
  const int z = blockIdx.z, b = b0 + z;
  const int Q0 = blockIdx.x * 128;
  const int kc = blockIdx.y;
  const int lane = tid & 63, w = tid >> 6;
  const int lrow = lane & 15, lg = lane >> 4;

  const unsigned short* qb = qT + (size_t)b * (4096 * 256);
  const unsigned short* kb = kT + (size_t)b * (4096 * 256);

  s16x8 af[2][8];
#pragma unroll
  for (int mt = 0; mt < 2; ++mt)
#pragma unroll
    for (int ks = 0; ks < 8; ++ks)
      af[mt][ks] = *(const s16x8*)(qb + (size_t)(Q0 + mt * 64 + w * 16 + lrow) * 256 + ks * 32 + lg * 8);

  float st_m[8], st_l[8];
#pragma unroll
  for (int s = 0; s < 8; ++s) { st_m[s] = 0.f; st_l[s] = 0.f; }

  int cur = 0;
  {
    const unsigned short* src = kb + (size_t)(kc * 1024) * 256;
#pragma unroll
    for (int rep = 0; rep < 8; ++rep) {
      int i = rep * 256 + tid;
      int row = i >> 5, c8 = i & 31;
      int c8s = c8 ^ (row & 7);
      gload16(src + (size_t)row * 256 + c8s * 8, &kbuf[0][(i - lane) * 8]);
    }
  }
  __syncthreads();

  for (int it = 0; it < 16; ++it) {
    if (it + 1 < 16) {
      const unsigned short* src = kb + (size_t)(kc * 1024 + (it + 1) * 64) * 256;
#pragma unroll
      for (int rep = 0; rep < 8; ++rep) {
        int i = rep * 256 + tid;
        int row = i >> 5, c8 = i & 31;
        int c8s = c8 ^ (row & 7);
        gload16(src + (size_t)row * 256 + c8s * 8, &kbuf[cur ^ 1][(i - lane) * 8]);
      }
    }
    f32x4 acc[2][4];
#pragma unroll
    for (int mt = 0; mt < 2; ++mt)
#pragma unroll
      for (int nt = 0; nt < 4; ++nt) acc[mt][nt] = (f32x4){0.f, 0.f, 0.f, 0.f};
#pragma unroll
    for (int ks = 0; ks < 8; ++ks) {
#pragma unroll
      for (int nt = 0; nt < 4; ++nt) {
        int row = nt * 16 + lrow;
        int ch = (ks * 4 + lg) ^ (row & 7);
        s16x8 bf = *(const s16x8*)&kbuf[cur][row * 256 + ch * 8];
        acc[0][nt] = __builtin_amdgcn_mfma_f32_16x16x32_bf16(af[0][ks], bf, acc[0][nt], 0, 0, 0);
        acc[1][nt] = __builtin_amdgcn_mfma_f32_16x16x32_bf16(af[1][ks], bf, acc[1][nt], 0, 0, 0);
      }
    }
    const int kt = kc * 16 + it;
#pragma unroll
    for (int mt = 0; mt < 2; ++mt) {
      float sb[4][4];
      unsigned short* tb = ST + (((size_t)(z * 64 + kt)) * 64 + (Q0 >> 6) + mt) * 4096;
#pragma unroll
      for (int nt = 0; nt < 4; ++nt) {
        ushort4 pk;
#pragma unroll
        for (int j = 0; j < 4; ++j) {
          unsigned short us = f2bf(acc[mt][nt][j]);
          ((unsigned short*)&pk)[j] = us;
          sb[nt][j] = __uint_as_float((unsigned int)us << 16);
        }
        *(ushort4*)(tb + (size_t)(nt * 16 + lrow) * 64 + w * 16 + lg * 4) = pk;
      }
#pragma unroll
      for (int j = 0; j < 4; ++j) {
        int s = mt * 4 + j;
        float mx = fmaxf(fmaxf(sb[0][j], sb[1][j]), fmaxf(sb[2][j], sb[3][j]));
        float mn = fmaxf(st_m[s], mx);
        st_l[s] = st_l[s] * __expf(st_m[s] - mn) +
                  __expf(sb[0][j] - mn) + __expf(sb[1][j] - mn) +
                  __expf(sb[2][j] - mn) + __expf(sb[3][j] - mn);
        st_m[s] = mn;
      }
    }
    __syncthreads();
    cur ^= 1;
  }
#pragma unroll
  for (int s = 0; s < 8; ++s) {
    float m = st_m[s], l = st_l[s];
#pragma unroll
    for (int o = 1; o < 16; o <<= 1) {
      float mo = __shfl_xor(m, o);
      float lo = __shfl_xor(l, o);
      float mn = fmaxf(m, mo);
      l = l * __expf(m - mn) + lo * __expf(mo - mn);
      m = mn;
    }
    st_m[s] = m; st_l[s] = l;
  }
  if (lrow == 0) {
    float* pmb = pm + ((size_t)b * KS1 + kc) * 4096;
    float* plb = pl + ((size_t)b * KS1 + kc) * 4096;
#pragma unroll
    for (int mt = 0; mt < 2; ++mt)
#pragma unroll
      for (int j = 0; j < 4; ++j) {
        int q = Q0 + mt * 64 + w * 16 + lg * 4 + j;
        pmb[q] = st_m[mt * 4 + j];
        plb[q] = st_l[mt * 4 + j];
      }
  }
}

__global__ __launch_bounds__(256) void stats_merge_k(const float* __restrict__ pm,
    const float* __restrict__ pl, float* __restrict__ ma, float* __restrict__ ra, int b0) {
  int i = blockIdx.x * 256 + threadIdx.x;
  int b = b0 + (i >> 12), q = i & 4095;
  const float* pmb = pm + (size_t)b * KS1 * 4096 + q;
  const float* plb = pl + (size_t)b * KS1 * 4096 + q;
  float m = -1e30f;
#pragma unroll
  for (int c = 0; c < KS1; ++c) m = fmaxf(m, pmb[(size_t)c * 4096]);
  float l = 0.f;
#pragma unroll
  for (int c = 0; c < KS1; ++c) l += plb[(size_t)c * 4096] * __expf(pmb[(size_t)c * 4096] - m);
  ma[(size_t)b * 4096 + q] = m;
  ra[(size_t)b * 4096 + q] = 1.f / l;
}

// ------------- pass 2 v3: PV from stored S^T; v direct global->reg -------------
// grid (64*G), 512 thr, 1 block/CU. Block owns k-tile 64 of batch b0+z.
__global__ __launch_bounds__(512) void attn_pv3_k(
    const unsigned short* __restrict__ ST,
    const unsigned short* __restrict__ vb,   // [B][C][T]
    const float* __restrict__ ma, const float* __restrict__ ra,
    unsigned short* __restrict__ aT, int b0, int G) {
  __shared__ unsigned short P[64 * 72];  // [k][q+pad], chunk-XOR swizzled
  const int tid = threadIdx.x;
  int pidx = blockIdx.x;
  int kt, z;
  if (G == 4) {  // XCD swizzle: batch z lives on XCD pair {2z, 2z+1}
    kt = ((pidx >> 3) << 1) | (pidx & 1);
    z = (pidx >> 1) & 3;
  } else {
    kt = pidx & 63;
    z = pidx >> 6;
  }
  const int b = b0 + z;
  const int K0 = kt * 64;
  const int lane = tid & 63, w = tid >> 6;
  const int lrow = lane & 15, lg = lane >> 4;
  const int kk_e = tid >> 3, o_e = tid & 7;
  const int se_e = o_e ^ ((kk_e >> 3) & 7);  // stored chunk (write side)

  const unsigned short* vg = vb + (size_t)b * (4096 * 256);
  const unsigned short* stg = ST + ((size_t)(z * 64 + kt) * 64) * 4096;
  const float* mg = ma + (size_t)b * 4096;
  const float* rg = ra + (size_t)b * 4096;

  f32x4 oacc[2][4];
#pragma unroll
  for (int mt = 0; mt < 2; ++mt)
#pragma unroll
    for (int nt = 0; nt < 4; ++nt) oacc[mt][nt] = (f32x4){0.f, 0.f, 0.f, 0.f};

#define LOADSV(SV, M0, M1, R0, R1, QT)                                \
  do {                                                                \
    SV = *(const u32x4*)(stg + (size_t)(QT)*4096 + tid * 8);          \
    M0 = *(const float4*)(mg + (QT)*64 + o_e * 8);                    \
    M1 = *(const float4*)(mg + (QT)*64 + o_e * 8 + 4);                \
    R0 = *(const float4*)(rg + (QT)*64 + o_e * 8);                    \
    R1 = *(const float4*)(rg + (QT)*64 + o_e * 8 + 4);                \
  } while (0)

#define LOADVF(DST, Q)                                                          \
  do {                                                                          \
    _Pragma("unroll") for (int mt = 0; mt < 2; ++mt)                            \
    _Pragma("unroll") for (int ks = 0; ks < 2; ++ks)                            \
      DST[mt * 2 + ks] = *(const s16x8*)(vg +                                   \
          (size_t)(w * 32 + mt * 16 + lrow) * 4096 + (Q) + ks * 32 + lg * 8);   \
  } while (0)

#define EXPST(SV, M0, M1, R0, R1)                                              \
  do {                                                                         \
    u32x4 pk_;                                                                 \
    { unsigned int u = SV[0];                                                  \
      float a0 = __expf(__uint_as_float(u << 16) - M0.x) * R0.x;               \
      float a1 = __expf(__uint_as_float(u & 0xffff0000u) - M0.y) * R0.y;       \
      pk_[0] = (unsigned int)f2bf(a0) | ((unsigned int)f2bf(a1) << 16); }      \
    { unsigned int u = SV[1];                                                  \
      float a0 = __expf(__uint_as_float(u << 16) - M0.z) * R0.z;               \
      float a1 = __expf(__uint_as_float(u & 0xffff0000u) - M0.w) * R0.w;       \
      pk_[1] = (unsigned int)f2bf(a0) | ((unsigned int)f2bf(a1) << 16); }      \
    { unsigned int u = SV[2];                                                  \
      float a0 = __expf(__uint_as_float(u << 16) - M1.x) * R1.x;               \
      float a1 = __expf(__uint_as_float(u & 0xffff0000u) - M1.y) * R1.y;       \
      pk_[2] = (unsigned int)f2bf(a0) | ((unsigned int)f2bf(a1) << 16); }      \
    { unsigned int u = SV[3];                                                  \
      float a0 = __expf(__uint_as_float(u << 16) - M1.z) * R1.z;               \
      float a1 = __expf(__uint_as_float(u & 0xffff0000u) - M1.w) * R1.w;       \
      pk_[3] = (unsigned int)f2bf(a0) | ((unsigned int)f2bf(a1) << 16); }      \
    *(u32x4*)&P[kk_e * 72 + se_e * 8] = pk_;                                   \
  } while (0)

#define PVSTEP(VF)                                                             \
  do {                                                                         \
    _Pragma("unroll") for (int ks = 0; ks < 2; ++ks) {                         \
      s16x8 pf[4];                                                             \
      _Pragma("unroll") for (int nt = 0; nt < 4; ++nt) {                       \
        int kk = nt * 16 + lrow;                                               \
        pf[nt] = *(const s16x8*)&P[kk * 72 + ((ks * 4 + lg) ^ ((kk >> 3) & 7)) * 8]; \
      }                                                                        \
      _Pragma("unroll") for (int mt = 0; mt < 2; ++mt)                         \
      _Pragma("unroll") for (int nt = 0; nt < 4; ++nt)                         \
        oacc[mt][nt] = __builtin_amdgcn_mfma_f32_16x16x32_bf16(                \
            VF[mt * 2 + ks], pf[nt], oacc[mt][nt], 0, 0, 0);                   \
    }                                                                          \
  } while (0)

  u32x4 svA, svB;
  float4 mA0, mA1, rA0, rA1, mB0, mB1, rB0, rB1;
  s16x8 vfA[4], vfB[4];

  // prologue: state for tile 0
  LOADSV(svA, mA0, mA1, rA0, rA1, 0);
  LOADVF(vfA, 0);

  for (int qi = 0; qi < 64; qi += 2) {
    // ---- half A: tile qi ----
    LOADSV(svB, mB0, mB1, rB0, rB1, qi + 1);
    EXPST(svA, mA0, mA1, rA0, rA1);
    __syncthreads();
    LOADVF(vfB, (qi + 1) * 64);
    PVSTEP(vfA);
    __syncthreads();
    // ---- half B: tile qi+1 ----
    const int qn = (qi + 2 < 64) ? (qi + 2) : 63;  // clamp (values unused on exit)
    LOADSV(svA, mA0, mA1, rA0, rA1, qn);
    EXPST(svB, mB0, mB1, rB0, rB1);
    __syncthreads();
    LOADVF(vfA, qn * 64);
    PVSTEP(vfB);
    __syncthreads();
  }

  // epilogue: aT[b][k][c]
  unsigned short* ab = aT + (size_t)b * (4096 * 256);
#pragma unroll
  for (int mt = 0; mt < 2; ++mt)
#pragma unroll
    for (int nt = 0; nt < 4; ++nt) {
      int k = K0 + nt * 16 + lrow;
      int c = w * 32 + mt * 16 + lg * 4;
      ushort4 pk;
      pk.x = f2bf(oacc[mt][nt][0]);
      pk.y = f2bf(oacc[mt][nt][1]);
      pk.z = f2bf(oacc[mt][nt][2]);
      pk.w = f2bf(oacc[mt][nt][3]);
      *(ushort4*)(ab + (size_t)k * 256 + c) = pk;
    }
#undef LOADSV
#undef LOADVF
#undef EXPST
#undef PVSTEP
}

extern "C" void kernel_launch(void* const* d_in, const int* in_sizes, int n_in,
                              void* d_out, int out_size, void* d_ws, size_t ws_size,
                              hipStream_t stream) {
  const float* x   = (const float*)d_in[0];
  const float* gns = (const float*)d_in[1];
  const float* gnb = (const float*)d_in[2];
  const float* wq  = (const float*)d_in[3];
  const float* bq  = (const float*)d_in[4];
  const float* wk  = (const float*)d_in[5];
  const float* bk  = (const float*)d_in[6];
  const float* wvp = (const float*)d_in[7];
  const float* bv  = (const float*)d_in[8];
  const float* wo  = (const float*)d_in[9];
  const float* bo  = (const float*)d_in[10];
  float* out = (float*)d_out;

  const int B = 4, C = 256, T = 4096;
  const long long TCe = (long long)T * C;

  char* p = (char*)d_ws;
  unsigned short* hT = (unsigned short*)p; p += (size_t)B * TCe * 2;
  unsigned short* qT = (unsigned short*)p; p += (size_t)B * TCe * 2;
  unsigned short* kT = (unsigned short*)p; p += (size_t)B * TCe * 2;
  unsigned short* vb = (unsigned short*)p; p += (size_t)B * TCe * 2;
  unsigned short* aT = (unsigned short*)p; p += (size_t)B * TCe * 2;
  float* gmean = (float*)p; p += 512;
  float* grstd = (float*)p; p += 512;
  float* pm = (float*)p; p += (size_t)B * KS1 * T * 4;
  float* pl = (float*)p; p += (size_t)B * KS1 * T * 4;
  float* ma = (float*)p; p += (size_t)B * T * 4;
  float* ra = (float*)p; p += (size_t)B * T * 4;
  unsigned short* ST = (unsigned short*)p;
  size_t used = (size_t)((char*)ST - (char*)d_ws);
  size_t avail = ws_size > used ? ws_size - used : 0;
  size_t perb = (size_t)T * T * 2;  // 32MB per batch of S^T
  int G = (avail >= 4 * perb) ? 4 : (avail >= 2 * perb) ? 2 : 1;

  // 1) GroupNorm
  gn_stats_k<<<B * 32, 256, 0, stream>>>(x, gmean, grstd);
  gn_apply_t_k<<<dim3(T / 64, C / 64, B), 256, 0, stream>>>(x, gns, gnb, gmean, grstd, hT);

  // 2) QKV projections (q folded with C^-0.5 = 1/16)
  gemm64_k<true, EPI_WT><<<dim3(T / 64, C / 64, B), 256, 0, stream>>>(
      wq, 0, C, hT, TCe, C, qT, TCe, C, bq, nullptr, 0, 0.0625f, C);
  gemm64_k<true, EPI_WT><<<dim3(T / 64, C / 64, B), 256, 0, stream>>>(
      wk, 0, C, hT, TCe, C, kT, TCe, C, bk, nullptr, 0, 1.0f, C);
  gemm64_k<true, EPI_PB><<<dim3(T / 64, C / 64, B), 256, 0, stream>>>(
      wvp, 0, C, hT, TCe, C, vb, TCe, T, bv, nullptr, 0, 1.0f, C);

  // 3) attention in batch groups sized by workspace
  for (int b0 = 0; b0 < B; b0 += G) {
    attn_stats2_k<<<dim3(T / 128, KS1, G), 256, 0, stream>>>(qT, kT, pm, pl, ST, b0);
    stats_merge_k<<<G * T / 256, 256, 0, stream>>>(pm, pl, ma, ra, b0);
    attn_pv3_k<<<dim3(64 * G), 512, 0, stream>>>(ST, vb, ma, ra, aT, b0, G);
  }

  // 4) final projection + bias + residual
  gemm64_k<true, EPI_FIN><<<dim3(T / 64, C / 64, B), 256, 0, stream>>>(
      wo, 0, C, aT, TCe, C, out, TCe, T, bo, x, TCe, 1.0f, C);
}

// Round 5
// 206.908 us; speedup vs baseline: 1.1307x; 1.0882x over previous
//
#include <hip/hip_runtime.h>

typedef float f32x4 __attribute__((ext_vector_type(4)));
typedef short s16x8 __attribute__((ext_vector_type(8)));

#define MOFF 12.0f

__device__ __forceinline__ unsigned short f2bf(float f) {
  unsigned int u = __float_as_uint(f);
  u += 0x7fffu + ((u >> 16) & 1u);
  return (unsigned short)(u >> 16);
}

template <typename T>
__device__ __forceinline__ void gload16(const T* g, T* l) {
  __builtin_amdgcn_global_load_lds(
      (const __attribute__((address_space(1))) void*)g,
      (__attribute__((address_space(3))) void*)l, 16, 0, 0);
}

// ---------------- GroupNorm stats: one block per (b,g) ----------------
__global__ __launch_bounds__(256) void gn_stats_k(const float* __restrict__ x,
                                                  float* __restrict__ meanv,
                                                  float* __restrict__ rstdv) {
  const int bg = blockIdx.x;
  const float4* base = (const float4*)(x + (size_t)bg * 8 * 4096);
  float s = 0.f, q = 0.f;
  for (int i = threadIdx.x; i < 8192; i += 256) {
    float4 v = base[i];
    s += v.x + v.y + v.z + v.w;
    q += v.x * v.x + v.y * v.y + v.z * v.z + v.w * v.w;
  }
  for (int o = 32; o; o >>= 1) { s += __shfl_down(s, o); q += __shfl_down(q, o); }
  __shared__ float ss[4], sq[4];
  const int wv = threadIdx.x >> 6;
  if ((threadIdx.x & 63) == 0) { ss[wv] = s; sq[wv] = q; }
  __syncthreads();
  if (threadIdx.x == 0) {
    s = ss[0] + ss[1] + ss[2] + ss[3];
    q = sq[0] + sq[1] + sq[2] + sq[3];
    float mu = s * (1.f / 32768.f);
    float var = q * (1.f / 32768.f) - mu * mu;
    meanv[bg] = mu;
    rstdv[bg] = rsqrtf(var + 1e-6f);
  }
}

// ------------- GroupNorm apply + transpose: write hT[b][t][c] bf16 -------------
__global__ __launch_bounds__(256) void gn_apply_t_k(const float* __restrict__ x,
    const float* __restrict__ gamma, const float* __restrict__ beta,
    const float* __restrict__ meanv, const float* __restrict__ rstdv,
    unsigned short* __restrict__ hT) {
  __shared__ unsigned short tile[64][72];
  const int b = blockIdx.z, c0 = blockIdx.y * 64, t0 = blockIdx.x * 64;
  const int tid = threadIdx.x;
  {
    const int tr = tid >> 4, tc = (tid & 15) * 4;
    const float* xb = x + ((size_t)b * 256 + c0) * 4096 + t0;
    for (int p2 = 0; p2 < 4; ++p2) {
      int cl = p2 * 16 + tr;
      int c = c0 + cl;
      int bg = b * 32 + (c >> 3);
      float ga = gamma[c] * rstdv[bg];
      float be = beta[c] - meanv[bg] * ga;
      float4 v = *(const float4*)(xb + (size_t)cl * 4096 + tc);
      tile[cl][tc + 0] = f2bf(v.x * ga + be);
      tile[cl][tc + 1] = f2bf(v.y * ga + be);
      tile[cl][tc + 2] = f2bf(v.z * ga + be);
      tile[cl][tc + 3] = f2bf(v.w * ga + be);
    }
  }
  __syncthreads();
  {
    const int orow = tid >> 3, oc = (tid & 7) * 8;
    unsigned short* hb = hT + ((size_t)b * 4096 + t0) * 256 + c0;
    for (int p2 = 0; p2 < 2; ++p2) {
      int tl = p2 * 32 + orow;
      s16x8 w;
#pragma unroll
      for (int j = 0; j < 8; ++j) w[j] = (short)tile[oc + j][tl];
      *(s16x8*)(hb + (size_t)tl * 256 + oc) = w;
    }
  }
}

// ---------------- generic 64x64-tile MFMA GEMM (projections) ----------------
enum { EPI_WT = 0, EPI_PB = 1, EPI_FIN = 3 };

template <bool AF32, int EPI>
__global__ __launch_bounds__(256) void gemm64_k(
    const void* __restrict__ Ap, long long sA, int lda,
    const unsigned short* __restrict__ Bp, long long sB, int ldb,
    void* __restrict__ Op, long long sO, int ldo,
    const float* __restrict__ bias,
    const float* __restrict__ xadd, long long sX,
    float scale, int K) {
  __shared__ s16x8 lsA[4][64];
  __shared__ s16x8 lsB[4][64];
  const int tid = threadIdx.x;
  const int m0 = blockIdx.y * 64, n0 = blockIdx.x * 64;
  const int z = blockIdx.z;
  const int lane = tid & 63, wv = tid >> 6;
  const int lrow = lane & 15, lg = lane >> 4;
  const int srow = tid >> 2, scg = tid & 3;
  const int swrow = srow ^ (scg << 1);

  f32x4 acc[4];
#pragma unroll
  for (int i = 0; i < 4; ++i) acc[i] = (f32x4){0.f, 0.f, 0.f, 0.f};

  const unsigned short* Bb = Bp + (size_t)z * sB + (size_t)(n0 + srow) * ldb + scg * 8;

  for (int k0 = 0; k0 < K; k0 += 32) {
    if (AF32) {
      const float* ap = (const float*)Ap + (size_t)z * sA + (size_t)(m0 + srow) * lda + k0 + scg * 8;
      float4 v0 = *(const float4*)ap;
      float4 v1 = *(const float4*)(ap + 4);
      s16x8 w;
      w[0] = (short)f2bf(v0.x); w[1] = (short)f2bf(v0.y);
      w[2] = (short)f2bf(v0.z); w[3] = (short)f2bf(v0.w);
      w[4] = (short)f2bf(v1.x); w[5] = (short)f2bf(v1.y);
      w[6] = (short)f2bf(v1.z); w[7] = (short)f2bf(v1.w);
      lsA[scg][swrow] = w;
    } else {
      const unsigned short* ap = (const unsigned short*)Ap + (size_t)z * sA + (size_t)(m0 + srow) * lda + k0 + scg * 8;
      lsA[scg][swrow] = *(const s16x8*)ap;
    }
    lsB[scg][swrow] = *(const s16x8*)(Bb + k0);
    __syncthreads();
    s16x8 af = lsA[lg][(wv * 16 + lrow) ^ (lg << 1)];
#pragma unroll
    for (int nt = 0; nt < 4; ++nt) {
      s16x8 bf = lsB[lg][(nt * 16 + lrow) ^ (lg << 1)];
      acc[nt] = __builtin_amdgcn_mfma_f32_16x16x32_bf16(af, bf, acc[nt], 0, 0, 0);
    }
    __syncthreads();
  }

  const int mb = m0 + wv * 16 + lg * 4;
  float bv0 = 0.f, bv1 = 0.f, bv2 = 0.f, bv3 = 0.f;
  if (bias) { bv0 = bias[mb]; bv1 = bias[mb + 1]; bv2 = bias[mb + 2]; bv3 = bias[mb + 3]; }
#pragma unroll
  for (int nt = 0; nt < 4; ++nt) {
    const int n = n0 + nt * 16 + lrow;
    if (EPI == EPI_WT) {
      ushort4 pk;
      pk.x = f2bf((acc[nt][0] + bv0) * scale);
      pk.y = f2bf((acc[nt][1] + bv1) * scale);
      pk.z = f2bf((acc[nt][2] + bv2) * scale);
      pk.w = f2bf((acc[nt][3] + bv3) * scale);
      *(ushort4*)((unsigned short*)Op + (size_t)z * sO + (size_t)n * ldo + mb) = pk;
    } else if (EPI == EPI_PB) {
      unsigned short* o = (unsigned short*)Op + (size_t)z * sO;
      o[(size_t)(mb + 0) * ldo + n] = f2bf(acc[nt][0] + bv0);
      o[(size_t)(mb + 1) * ldo + n] = f2bf(acc[nt][1] + bv1);
      o[(size_t)(mb + 2) * ldo + n] = f2bf(acc[nt][2] + bv2);
      o[(size_t)(mb + 3) * ldo + n] = f2bf(acc[nt][3] + bv3);
    } else {
      float* o = (float*)Op + (size_t)z * sO;
      const float* xa = xadd + (size_t)z * sX;
      o[(size_t)(mb + 0) * ldo + n] = acc[nt][0] + bv0 + xa[(size_t)(mb + 0) * ldo + n];
      o[(size_t)(mb + 1) * ldo + n] = acc[nt][1] + bv1 + xa[(size_t)(mb + 1) * ldo + n];
      o[(size_t)(mb + 2) * ldo + n] = acc[nt][2] + bv2 + xa[(size_t)(mb + 2) * ldo + n];
      o[(size_t)(mb + 3) * ldo + n] = acc[nt][3] + bv3 + xa[(size_t)(mb + 3) * ldo + n];
    }
  }
}

// ------- pass 1: l[q] = sum_k exp(S - MOFF), fixed offset, no max tracking -------
// grid (T/256, 8, B), 256 thr. Block: 256 q rows (reg-pinned) x 512 k.
__global__ __launch_bounds__(256) void attn_stats3_k(
    const unsigned short* __restrict__ qT,
    const unsigned short* __restrict__ kT,
    float* __restrict__ pl) {  // [8][B][T] partial sums
  __shared__ unsigned short kbuf[2][64 * 256];
  const int tid = threadIdx.x;
  const int b = blockIdx.z;
  const int Q0 = blockIdx.x * 256;
  const int kc = blockIdx.y;  // k strip [kc*512, +512)
  const int lane = tid & 63, wq = tid >> 6;
  const int lrow = lane & 15, lg = lane >> 4;

  const unsigned short* qb = qT + (size_t)b * (4096 * 256);
  const unsigned short* kb = kT + (size_t)b * (4096 * 256);

  // A-frags: 64 q rows per wave, pinned (4x reuse of every staged B byte)
  s16x8 af[4][8];
#pragma unroll
  for (int mt = 0; mt < 4; ++mt)
#pragma unroll
    for (int ks = 0; ks < 8; ++ks)
      af[mt][ks] = *(const s16x8*)(qb + (size_t)(Q0 + wq * 64 + mt * 16 + lrow) * 256 + ks * 32 + lg * 8);

  float sl[4][4];
#pragma unroll
  for (int mt = 0; mt < 4; ++mt)
#pragma unroll
    for (int j = 0; j < 4; ++j) sl[mt][j] = 0.f;

  int cur = 0;
  {  // prologue stage
    const unsigned short* src = kb + (size_t)(kc * 512) * 256;
#pragma unroll
    for (int rep = 0; rep < 8; ++rep) {
      int i = rep * 256 + tid;
      int row = i >> 5, c8 = i & 31;
      gload16(src + (size_t)row * 256 + (c8 ^ (row & 7)) * 8, &kbuf[0][(i - lane) * 8]);
    }
  }
  __syncthreads();

  for (int it = 0; it < 8; ++it) {
    if (it + 1 < 8) {
      const unsigned short* src = kb + (size_t)(kc * 512 + (it + 1) * 64) * 256;
#pragma unroll
      for (int rep = 0; rep < 8; ++rep) {
        int i = rep * 256 + tid;
        int row = i >> 5, c8 = i & 31;
        gload16(src + (size_t)row * 256 + (c8 ^ (row & 7)) * 8, &kbuf[cur ^ 1][(i - lane) * 8]);
      }
    }
#pragma unroll
    for (int nt = 0; nt < 4; ++nt) {
      f32x4 acc[4];
#pragma unroll
      for (int mt = 0; mt < 4; ++mt) acc[mt] = (f32x4){0.f, 0.f, 0.f, 0.f};
#pragma unroll
      for (int ks = 0; ks < 8; ++ks) {
        int row = nt * 16 + lrow;
        int ch = (ks * 4 + lg) ^ (row & 7);
        s16x8 bf = *(const s16x8*)&kbuf[cur][row * 256 + ch * 8];
#pragma unroll
        for (int mt = 0; mt < 4; ++mt)
          acc[mt] = __builtin_amdgcn_mfma_f32_16x16x32_bf16(af[mt][ks], bf, acc[mt], 0, 0, 0);
      }
#pragma unroll
      for (int mt = 0; mt < 4; ++mt)
#pragma unroll
        for (int j = 0; j < 4; ++j) sl[mt][j] += __expf(acc[mt][j] - MOFF);
    }
    __syncthreads();
    cur ^= 1;
  }
  // reduce over the 16 lrow lanes (k columns)
#pragma unroll
  for (int mt = 0; mt < 4; ++mt)
#pragma unroll
    for (int j = 0; j < 4; ++j) {
      float v = sl[mt][j];
      v += __shfl_xor(v, 1);
      v += __shfl_xor(v, 2);
      v += __shfl_xor(v, 4);
      v += __shfl_xor(v, 8);
      sl[mt][j] = v;
    }
  if (lrow == 0) {
    float* plb = pl + ((size_t)kc * 4 + b) * 4096;
#pragma unroll
    for (int mt = 0; mt < 4; ++mt)
#pragma unroll
      for (int j = 0; j < 4; ++j)
        plb[Q0 + wq * 64 + mt * 16 + lg * 4 + j] = sl[mt][j];
  }
}

// r[q] = 1 / sum_kc pl
__global__ __launch_bounds__(256) void make_r_k(const float* __restrict__ pl,
                                                float* __restrict__ ra) {
  int i = blockIdx.x * 256 + threadIdx.x;  // B*T
  int b = i >> 12, q = i & 4095;
  float l = 0.f;
#pragma unroll
  for (int kc = 0; kc < 8; ++kc) l += pl[((size_t)kc * 4 + b) * 4096 + q];
  ra[i] = 1.f / l;
}

// ------- pass 2: fused S-recompute + exp + PV. grid 256 (1/CU), 512 thr -------
// Block owns k-tile [K0,K0+64) of batch z; streams q in tiles of 128.
__global__ __launch_bounds__(512) void attn_pv5_k(
    const unsigned short* __restrict__ qT,
    const unsigned short* __restrict__ kT,
    const unsigned short* __restrict__ vb,   // [B][C][T]
    const float* __restrict__ ra,            // [B][T]
    unsigned short* __restrict__ aT) {       // [B][T][C]
  __shared__ unsigned short qbuf[2][128 * 256];  // 64KB x2
  __shared__ unsigned short P[64 * 128];         // 16KB, chunk-XOR swizzled
  const int tid = threadIdx.x;
  const int pidx = blockIdx.x;
  const int z = (pidx >> 1) & 3;                       // batch -> XCD pair
  const int kt = ((pidx >> 3) << 1) | (pidx & 1);      // 0..63
  const int K0 = kt * 64;
  const int lane = tid & 63, w = tid >> 6;
  const int lrow = lane & 15, lg = lane >> 4;
  const int khw = w >> 2;   // k-half (32 rows) this wave computes in S phase
  const int qqw = w & 3;    // q-quarter (32 cols) this wave computes in S phase

  const unsigned short* qg = qT + (size_t)z * (4096 * 256);
  const unsigned short* kg = kT + (size_t)z * (4096 * 256);
  const unsigned short* vg = vb + (size_t)z * (4096 * 256);
  const float* rg = ra + (size_t)z * 4096;

  // pinned kf: A-operand rows K0+khw*32 .. +32 (2 tiles x 8 ks)
  s16x8 kf[2][8];
#pragma unroll
  for (int ktl = 0; ktl < 2; ++ktl)
#pragma unroll
    for (int ks = 0; ks < 8; ++ks)
      kf[ktl][ks] = *(const s16x8*)(kg + (size_t)(K0 + khw * 32 + ktl * 16 + lrow) * 256 + ks * 32 + lg * 8);

  f32x4 oacc[2][4];  // out c-tiles (w*32 + ct*16) x k-tiles (nt*16)
#pragma unroll
  for (int ct = 0; ct < 2; ++ct)
#pragma unroll
    for (int nt = 0; nt < 4; ++nt) oacc[ct][nt] = (f32x4){0.f, 0.f, 0.f, 0.f};

  int cur = 0;
  {  // prologue: stage q-tile 0 (128 rows x 512B), pre-swizzled source
#pragma unroll
    for (int rep = 0; rep < 8; ++rep) {
      int i = rep * 512 + tid;
      int row = i >> 5, c8 = i & 31;
      gload16(qg + (size_t)row * 256 + (c8 ^ (row & 7)) * 8, &qbuf[0][(i - lane) * 8]);
    }
  }
  __syncthreads();

  for (int qi = 0; qi < 32; ++qi) {
    const int q0 = qi * 128;
    // v fragments for this iter's PV: global -> reg, in flight through S phase
    s16x8 vf[2][4];
#pragma unroll
    for (int ct = 0; ct < 2; ++ct)
#pragma unroll
      for (int qs = 0; qs < 4; ++qs)
        vf[ct][qs] = *(const s16x8*)(vg + (size_t)(w * 32 + ct * 16 + lrow) * 4096 + q0 + qs * 32 + lg * 8);
    // stage next q-tile
    if (qi + 1 < 32) {
      const unsigned short* src = qg + (size_t)(q0 + 128) * 256;
#pragma unroll
      for (int rep = 0; rep < 8; ++rep) {
        int i = rep * 512 + tid;
        int row = i >> 5, c8 = i & 31;
        gload16(src + (size_t)row * 256 + (c8 ^ (row & 7)) * 8, &qbuf[cur ^ 1][(i - lane) * 8]);
      }
    }
    // S phase: S^T quadrant [khw*32 .. +32][qqw*32 .. +32]
    f32x4 sacc[2][2];
#pragma unroll
    for (int ktl = 0; ktl < 2; ++ktl)
#pragma unroll
      for (int qt = 0; qt < 2; ++qt) sacc[ktl][qt] = (f32x4){0.f, 0.f, 0.f, 0.f};
#pragma unroll
    for (int qt = 0; qt < 2; ++qt) {
#pragma unroll
      for (int ks = 0; ks < 8; ++ks) {
        int row = qqw * 32 + qt * 16 + lrow;
        int ch = (ks * 4 + lg) ^ (row & 7);
        s16x8 qf = *(const s16x8*)&qbuf[cur][row * 256 + ch * 8];
        sacc[0][qt] = __builtin_amdgcn_mfma_f32_16x16x32_bf16(kf[0][ks], qf, sacc[0][qt], 0, 0, 0);
        sacc[1][qt] = __builtin_amdgcn_mfma_f32_16x16x32_bf16(kf[1][ks], qf, sacc[1][qt], 0, 0, 0);
      }
    }
    // exp and write P (bf16), swizzled: elem (k,q) at short index k*128 + ((q>>3)^(k&7))*8 + (q&7)
#pragma unroll
    for (int qt = 0; qt < 2; ++qt) {
      const int ql = qqw * 32 + qt * 16 + lrow;
      const float rv = rg[q0 + ql];
#pragma unroll
      for (int ktl = 0; ktl < 2; ++ktl)
#pragma unroll
        for (int j = 0; j < 4; ++j) {
          int k = khw * 32 + ktl * 16 + lg * 4 + j;
          float p = __expf(sacc[ktl][qt][j] - MOFF) * rv;
          P[k * 128 + (((ql >> 3) ^ (k & 7)) << 3) + (ql & 7)] = f2bf(p);
        }
    }
    __syncthreads();  // P visible; next q-tile staged (vmcnt drained)
    // PV: oacc[c][k] += v[c][q-tile] * P^T[k][q-tile]
#pragma unroll
    for (int qs = 0; qs < 4; ++qs) {
      s16x8 pf[4];
#pragma unroll
      for (int nt = 0; nt < 4; ++nt) {
        int k = nt * 16 + lrow;
        pf[nt] = *(const s16x8*)&P[k * 128 + (((qs * 4 + lg) ^ (k & 7)) << 3)];
      }
#pragma unroll
      for (int ct = 0; ct < 2; ++ct)
#pragma unroll
        for (int nt = 0; nt < 4; ++nt)
          oacc[ct][nt] = __builtin_amdgcn_mfma_f32_16x16x32_bf16(vf[ct][qs], pf[nt], oacc[ct][nt], 0, 0, 0);
    }
    __syncthreads();  // P consumed; safe to overwrite next iter
    cur ^= 1;
  }
  // epilogue: aT[z][K0+k][c]
  unsigned short* ab = aT + (size_t)z * (4096 * 256);
#pragma unroll
  for (int ct = 0; ct < 2; ++ct)
#pragma unroll
    for (int nt = 0; nt < 4; ++nt) {
      int k = K0 + nt * 16 + lrow;
      int c = w * 32 + ct * 16 + lg * 4;
      ushort4 pk;
      pk.x = f2bf(oacc[ct][nt][0]);
      pk.y = f2bf(oacc[ct][nt][1]);
      pk.z = f2bf(oacc[ct][nt][2]);
      pk.w = f2bf(oacc[ct][nt][3]);
      *(ushort4*)(ab + (size_t)k * 256 + c) = pk;
    }
}

extern "C" void kernel_launch(void* const* d_in, const int* in_sizes, int n_in,
                              void* d_out, int out_size, void* d_ws, size_t ws_size,
                              hipStream_t stream) {
  const float* x   = (const float*)d_in[0];
  const float* gns = (const float*)d_in[1];
  const float* gnb = (const float*)d_in[2];
  const float* wq  = (const float*)d_in[3];
  const float* bq  = (const float*)d_in[4];
  const float* wk  = (const float*)d_in[5];
  const float* bk  = (const float*)d_in[6];
  const float* wvp = (const float*)d_in[7];
  const float* bv  = (const float*)d_in[8];
  const float* wo  = (const float*)d_in[9];
  const float* bo  = (const float*)d_in[10];
  float* out = (float*)d_out;

  const int B = 4, C = 256, T = 4096;
  const long long TCe = (long long)T * C;

  char* p = (char*)d_ws;
  unsigned short* hT = (unsigned short*)p; p += (size_t)B * TCe * 2;
  unsigned short* qT = (unsigned short*)p; p += (size_t)B * TCe * 2;
  unsigned short* kT = (unsigned short*)p; p += (size_t)B * TCe * 2;
  unsigned short* vb = (unsigned short*)p; p += (size_t)B * TCe * 2;
  unsigned short* aT = (unsigned short*)p; p += (size_t)B * TCe * 2;
  float* gmean = (float*)p; p += 512;
  float* grstd = (float*)p; p += 512;
  float* pl = (float*)p; p += (size_t)8 * B * T * 4;
  float* ra = (float*)p; p += (size_t)B * T * 4;

  // 1) GroupNorm
  gn_stats_k<<<B * 32, 256, 0, stream>>>(x, gmean, grstd);
  gn_apply_t_k<<<dim3(T / 64, C / 64, B), 256, 0, stream>>>(x, gns, gnb, gmean, grstd, hT);

  // 2) QKV projections (q folded with C^-0.5 = 1/16)
  gemm64_k<true, EPI_WT><<<dim3(T / 64, C / 64, B), 256, 0, stream>>>(
      wq, 0, C, hT, TCe, C, qT, TCe, C, bq, nullptr, 0, 0.0625f, C);
  gemm64_k<true, EPI_WT><<<dim3(T / 64, C / 64, B), 256, 0, stream>>>(
      wk, 0, C, hT, TCe, C, kT, TCe, C, bk, nullptr, 0, 1.0f, C);
  gemm64_k<true, EPI_PB><<<dim3(T / 64, C / 64, B), 256, 0, stream>>>(
      wvp, 0, C, hT, TCe, C, vb, TCe, T, bv, nullptr, 0, 1.0f, C);

  // 3) attention: denominators, reciprocal, fused recompute+PV
  attn_stats3_k<<<dim3(T / 256, 8, B), 256, 0, stream>>>(qT, kT, pl);
  make_r_k<<<B * T / 256, 256, 0, stream>>>(pl, ra);
  attn_pv5_k<<<256, 512, 0, stream>>>(qT, kT, vb, ra, aT);

  // 4) final projection + bias + residual
  gemm64_k<true, EPI_FIN><<<dim3(T / 64, C / 64, B), 256, 0, stream>>>(
      wo, 0, C, aT, TCe, C, out, TCe, T, bo, x, TCe, 1.0f, C);
}